// Round 17
// baseline (2069.100 us; speedup 1.0000x reference)
//
#include <hip/hip_runtime.h>
#include <hip/hip_bf16.h>
#include <math.h>

#define HIDDEN 256
#define NHEADS 8
#define DHEAD  32
#define NT     50000
#define NC     50000
#define NTOT   (NT + NC)
#define ET_N   800000
#define EC_N   800000

typedef __hip_bfloat16 bf16;

// ---------------------------------------------------------------- utilities
static __device__ __forceinline__ float b2f(unsigned short u) {
  union { unsigned int i; float f; } c;
  c.i = ((unsigned int)u) << 16;
  return c.f;
}
static __device__ __forceinline__ unsigned short f2b(float f) {
  bf16 h = __float2bfloat16(f);  // RNE
  return *reinterpret_cast<unsigned short*>(&h);
}
static __device__ __forceinline__ float4 load4(const float* p) {
  return *reinterpret_cast<const float4*>(p);
}
static __device__ __forceinline__ float4 load4(const bf16* p) {
  ushort4 u = *reinterpret_cast<const ushort4*>(p);
  return make_float4(b2f(u.x), b2f(u.y), b2f(u.z), b2f(u.w));
}
static __device__ __forceinline__ void store4(float* p, float a, float b, float c, float d) {
  *reinterpret_cast<float4*>(p) = make_float4(a, b, c, d);
}
static __device__ __forceinline__ void store4(bf16* p, float a, float b, float c, float d) {
  ushort4 u;
  u.x = f2b(a); u.y = f2b(b); u.z = f2b(c); u.w = f2b(d);
  *reinterpret_cast<ushort4*>(p) = u;
}

static __device__ __forceinline__ float wave_sum64(float v) {
#pragma unroll
  for (int m = 1; m < 64; m <<= 1) v += __shfl_xor(v, m, 64);
  return v;
}

static __device__ __forceinline__ float gelu_exact(float g) {
  return 0.5f * g * (1.0f + erff(g * 0.70710678118654752440f));
}

// ------------------------------------------------------- LayerNorm (1 wave/row)
// x: TI[nrow][256] (fp32 or bf16), w/b: fp32[256], y: bf16[nrow][256]; fp32 stats
template <typename TI>
__global__ __launch_bounds__(256) void ln_kernel(const TI* __restrict__ x,
                                                 const float* __restrict__ w,
                                                 const float* __restrict__ b,
                                                 bf16* __restrict__ y, int nrow) {
  int row = blockIdx.x * 4 + (threadIdx.x >> 6);
  if (row >= nrow) return;
  int lane = threadIdx.x & 63;
  const float4 xv = load4(x + (size_t)row * HIDDEN + lane * 4);
  float s = xv.x + xv.y + xv.z + xv.w;
  s = wave_sum64(s);
  float mean = s * (1.0f / HIDDEN);
  float dx = xv.x - mean, dy = xv.y - mean, dz = xv.z - mean, dw = xv.w - mean;
  float sq = dx * dx + dy * dy + dz * dz + dw * dw;
  sq = wave_sum64(sq);
  float inv = rsqrtf(sq * (1.0f / HIDDEN) + 1e-5f);
  const float4 wv = load4(w + lane * 4);
  const float4 bv = load4(b + lane * 4);
  store4(y + (size_t)row * HIDDEN + lane * 4,
         dx * inv * wv.x + bv.x, dy * inv * wv.y + bv.y,
         dz * inv * wv.z + bv.z, dw * inv * wv.w + bv.w);
}

// ------------------------------------------------------------------- GEMM
// C[M,256] = A[M,256] @ W[256,256] + bias; W/bias fp32, A/resid/out typed.
// fp32 LDS tiles + fp32 accumulate.
// MODE 0: out = val;  MODE 1: out = resid + val;  MODE 2: out = gelu(val)
template <int MODE, typename TA, typename TR, typename TO>
__global__ __launch_bounds__(256) void gemm_kernel(const TA* __restrict__ A, int M,
                                                   const float* __restrict__ W,
                                                   const float* __restrict__ bias,
                                                   const TR* __restrict__ resid,
                                                   TO* __restrict__ out) {
  __shared__ float As[16][64];  // [k][row] (transposed tile)
  __shared__ float Bs[16][64];  // [k][col]
  const int t = threadIdx.x;
  const int bm = blockIdx.x, cb = blockIdx.y;
  const int ty = t >> 4, tx = t & 15;
  const int ar = t >> 2;         // 0..63  row within tile (A staging)
  const int ak = (t & 3) * 4;    // 0,4,8,12
  const int bk = t >> 4;         // 0..15
  const int bc = (t & 15) * 4;   // 0..60
  const long arow = (long)bm * 64 + ar;
  const int c0 = cb * 64;

  float acc[4][4] = {};

  for (int kk = 0; kk < 256; kk += 16) {
    float4 a4 = make_float4(0.f, 0.f, 0.f, 0.f);
    if (arow < M) a4 = load4(A + arow * 256 + kk + ak);
    const float4 b4 = load4(W + (long)(kk + bk) * 256 + c0 + bc);
    __syncthreads();  // protect readers of previous tile
    As[ak + 0][ar] = a4.x;
    As[ak + 1][ar] = a4.y;
    As[ak + 2][ar] = a4.z;
    As[ak + 3][ar] = a4.w;
    Bs[bk][bc + 0] = b4.x;
    Bs[bk][bc + 1] = b4.y;
    Bs[bk][bc + 2] = b4.z;
    Bs[bk][bc + 3] = b4.w;
    __syncthreads();
#pragma unroll
    for (int k = 0; k < 16; ++k) {
      const float4 av = *reinterpret_cast<const float4*>(&As[k][ty * 4]);
      const float4 bv = *reinterpret_cast<const float4*>(&Bs[k][tx * 4]);
      const float aa[4] = {av.x, av.y, av.z, av.w};
      const float bb[4] = {bv.x, bv.y, bv.z, bv.w};
#pragma unroll
      for (int i = 0; i < 4; ++i)
#pragma unroll
        for (int j = 0; j < 4; ++j) acc[i][j] = fmaf(aa[i], bb[j], acc[i][j]);
    }
  }

  const float4 bv4 = load4(bias + c0 + tx * 4);
  const float bvals[4] = {bv4.x, bv4.y, bv4.z, bv4.w};
#pragma unroll
  for (int i = 0; i < 4; ++i) {
    const long r = (long)bm * 64 + ty * 4 + i;
    if (r >= M) break;
    float v0 = acc[i][0] + bvals[0];
    float v1 = acc[i][1] + bvals[1];
    float v2 = acc[i][2] + bvals[2];
    float v3 = acc[i][3] + bvals[3];
    if (MODE == 1) {
      const float4 rv = load4(resid + r * 256 + c0 + tx * 4);
      v0 += rv.x; v1 += rv.y; v2 += rv.z; v3 += rv.w;
    }
    if (MODE == 2) {
      v0 = gelu_exact(v0); v1 = gelu_exact(v1);
      v2 = gelu_exact(v2); v3 = gelu_exact(v3);
    }
    store4(out + r * 256 + c0 + tx * 4, v0, v1, v2, v3);
  }
}

// -------------------------------------------------------------- CSR build
__global__ void hist_kernel(const int* __restrict__ rows, int ne, int* __restrict__ cnt) {
  int i = blockIdx.x * blockDim.x + threadIdx.x;
  if (i < ne) atomicAdd(&cnt[rows[i]], 1);
}

__global__ __launch_bounds__(1024) void scan_kernel(const int* __restrict__ cnt, int n,
                                                    int* __restrict__ offs,
                                                    int* __restrict__ cur) {
  __shared__ int part[1024];
  const int t = threadIdx.x;
  const int chunk = (n + 1023) >> 10;
  const int begin = t * chunk;
  const int end = min(begin + chunk, n);
  int sum = 0;
  for (int i = begin; i < end; ++i) sum += cnt[i];
  part[t] = sum;
  __syncthreads();
  for (int off = 1; off < 1024; off <<= 1) {
    int val = (t >= off) ? part[t - off] : 0;
    __syncthreads();
    part[t] += val;
    __syncthreads();
  }
  int ex = (t == 0) ? 0 : part[t - 1];
  for (int i = begin; i < end; ++i) {
    offs[i] = ex;
    cur[i] = ex;
    ex += cnt[i];
  }
  if (t == 1023) offs[n] = part[1023];
}

__global__ void scatter_kernel(const int* __restrict__ rows, int ne, int* __restrict__ cur,
                               int* __restrict__ elist) {
  int i = blockIdx.x * blockDim.x + threadIdx.x;
  if (i < ne) {
    int p = atomicAdd(&cur[rows[i]], 1);
    elist[p] = i;
  }
}

// ---------------------------------------------------------- sparse attention
// one wave per output row; 8 lanes per head, 4 dims per lane; online softmax.
// q/k/v/o: bf16[*][256]; bias: fp32[ne][8]; fp32 state.
__global__ __launch_bounds__(256) void attn_kernel(const bf16* __restrict__ q,
                                                   const bf16* __restrict__ k,
                                                   const bf16* __restrict__ v,
                                                   const int* __restrict__ col,
                                                   const float* __restrict__ bias,
                                                   const int* __restrict__ offs,
                                                   const int* __restrict__ elist,
                                                   bf16* __restrict__ o, int nrow) {
  const int row = blockIdx.x * 4 + (threadIdx.x >> 6);
  if (row >= nrow) return;
  const int lane = threadIdx.x & 63;
  const int h = lane >> 3;
  const float4 q4 = load4(q + (size_t)row * HIDDEN + lane * 4);
  const int s0 = offs[row], s1 = offs[row + 1];
  float m = -INFINITY, z = 0.f;
  float4 o4 = make_float4(0.f, 0.f, 0.f, 0.f);
  for (int i = s0; i < s1; ++i) {
    const int eid = elist[i];
    const int c = col[eid];
    const float4 k4 = load4(k + (size_t)c * HIDDEN + lane * 4);
    float d = q4.x * k4.x + q4.y * k4.y + q4.z * k4.z + q4.w * k4.w;
    d += __shfl_xor(d, 1, 64);
    d += __shfl_xor(d, 2, 64);
    d += __shfl_xor(d, 4, 64);
    const float sc = d * 0.17677669529663689f + bias[(size_t)eid * NHEADS + h];
    const float mn = fmaxf(m, sc);
    const float f = __expf(m - mn);   // m=-inf -> 0
    const float p = __expf(sc - mn);
    z = z * f + p;
    const float4 v4 = load4(v + (size_t)c * HIDDEN + lane * 4);
    o4.x = o4.x * f + p * v4.x;
    o4.y = o4.y * f + p * v4.y;
    o4.z = o4.z * f + p * v4.z;
    o4.w = o4.w * f + p * v4.w;
    m = mn;
  }
  const float inv = 1.0f / (z + 1e-16f);
  store4(o + (size_t)row * HIDDEN + lane * 4, o4.x * inv, o4.y * inv, o4.z * inv, o4.w * inv);
}

// ----------------------------------------------------------------- launch
extern "C" void kernel_launch(void* const* d_in, const int* in_sizes, int n_in,
                              void* d_out, int out_size, void* d_ws, size_t ws_size,
                              hipStream_t stream) {
  const float* x_all  = (const float*)d_in[0];
  const float* bias_t = (const float*)d_in[1];
  const float* bias_c = (const float*)d_in[2];
  const int*   t_row  = (const int*)d_in[3];
  const int*   t_col  = (const int*)d_in[4];
  const int*   c_row  = (const int*)d_in[5];
  const int*   c_col  = (const int*)d_in[6];
  // d_in[7], d_in[8]: node-size scalars (compile-time constants here)
  const float* ln1_w = (const float*)d_in[9];
  const float* ln1_b = (const float*)d_in[10];
  const float* q1_w = (const float*)d_in[11];
  const float* q1_b = (const float*)d_in[12];
  const float* k1_w = (const float*)d_in[13];
  const float* k1_b = (const float*)d_in[14];
  const float* v1_w = (const float*)d_in[15];
  const float* v1_b = (const float*)d_in[16];
  const float* o1_w = (const float*)d_in[17];
  const float* o1_b = (const float*)d_in[18];
  const float* q2_w = (const float*)d_in[19];
  const float* q2_b = (const float*)d_in[20];
  const float* k2_w = (const float*)d_in[21];
  const float* k2_b = (const float*)d_in[22];
  const float* v2_w = (const float*)d_in[23];
  const float* v2_b = (const float*)d_in[24];
  const float* o2_w = (const float*)d_in[25];
  const float* o2_b = (const float*)d_in[26];
  const float* ln2_w = (const float*)d_in[27];
  const float* ln2_b = (const float*)d_in[28];
  const float* f1_w = (const float*)d_in[29];
  const float* f1_b = (const float*)d_in[30];
  const float* f2_w = (const float*)d_in[31];
  const float* f2_b = (const float*)d_in[32];

  // Workspace: bf16 intermediates, total ≈ 186.4 MB (proven to fit ws_size).
  //   [0,      12.8M)  Qb   \
  //   [12.8M,  25.6M)  Kb    } X (25.6M) overlays Q+K after attn2
  //   [25.6M,  38.4M)  Vb   \
  //   [38.4M,  51.2M)  O1    } H (25.6M) overlays V+O1 after O-proj1
  //   [51.2M,  64.0M)  O2
  //   [64.0M,  89.6M)  Y (LN1 out); Y2 overlays after QKV GEMMs
  //   ints at byte 179.2MB: cnt/off/cur/elists = 7.2 MB
  bf16* bws = (bf16*)d_ws;
  bf16* Qb = bws;
  bf16* Kb = bws + 12800000ULL;
  bf16* Vb = bws + 25600000ULL;
  bf16* X  = bws;                 // overlays Qb/Kb (dead after attn2)
  bf16* O1 = bws + 38400000ULL;
  bf16* O2 = bws + 51200000ULL;
  bf16* H  = bws + 25600000ULL;   // overlays Vb/O1 (dead after O-proj of O1)
  bf16* Y  = bws + 64000000ULL;
  bf16* Y2 = Y;                   // overlays Y (dead after QKV GEMMs)
  int* ib    = (int*)(bws + 89600000ULL);
  int* cnt_t = ib;
  int* cnt_c = cnt_t + NT;
  int* off_t = cnt_c + NC;        // NT+1
  int* off_c = off_t + (NT + 1);  // NC+1
  int* cur_t = off_c + (NC + 1);
  int* cur_c = cur_t + NT;
  int* el_t  = cur_c + NC;
  int* el_c  = el_t + ET_N;

  (void)hipMemsetAsync(cnt_t, 0, (size_t)(NT + NC) * sizeof(int), stream);

  // LN1 (fp32 in -> bf16 out)
  ln_kernel<float><<<(NTOT + 3) / 4, 256, 0, stream>>>(x_all, ln1_w, ln1_b, Y, NTOT);

  // CSR build (both edge sets)
  hist_kernel<<<(ET_N + 255) / 256, 256, 0, stream>>>(t_row, ET_N, cnt_t);
  hist_kernel<<<(EC_N + 255) / 256, 256, 0, stream>>>(c_row, EC_N, cnt_c);
  scan_kernel<<<1, 1024, 0, stream>>>(cnt_t, NT, off_t, cur_t);
  scan_kernel<<<1, 1024, 0, stream>>>(cnt_c, NC, off_c, cur_c);
  scatter_kernel<<<(ET_N + 255) / 256, 256, 0, stream>>>(t_row, ET_N, cur_t, el_t);
  scatter_kernel<<<(EC_N + 255) / 256, 256, 0, stream>>>(c_row, EC_N, cur_c, el_c);

  dim3 g50((NT + 63) / 64, 4), g100((NTOT + 63) / 64, 4);
  const bf16* Yt = Y;                          // target rows of LN1 out
  const bf16* Yc = Y + (size_t)NT * HIDDEN;    // context rows
  const bf16* nb = nullptr;                    // unused resid

  // ---- side 1: q from target, k/v from context; segments over t_row (NT rows)
  gemm_kernel<0, bf16, bf16, bf16><<<g50, 256, 0, stream>>>(Yt, NT, q1_w, q1_b, nb, Qb);
  gemm_kernel<0, bf16, bf16, bf16><<<g50, 256, 0, stream>>>(Yc, NC, k1_w, k1_b, nb, Kb);
  gemm_kernel<0, bf16, bf16, bf16><<<g50, 256, 0, stream>>>(Yc, NC, v1_w, v1_b, nb, Vb);
  attn_kernel<<<(NT + 3) / 4, 256, 0, stream>>>(Qb, Kb, Vb, t_col, bias_t, off_t, el_t, O1, NT);

  // ---- side 2: q from context, k/v from target; segments over c_row (NC rows)
  gemm_kernel<0, bf16, bf16, bf16><<<g50, 256, 0, stream>>>(Yc, NC, q2_w, q2_b, nb, Qb);
  gemm_kernel<0, bf16, bf16, bf16><<<g50, 256, 0, stream>>>(Yt, NT, k2_w, k2_b, nb, Kb);
  gemm_kernel<0, bf16, bf16, bf16><<<g50, 256, 0, stream>>>(Yt, NT, v2_w, v2_b, nb, Vb);
  attn_kernel<<<(NC + 3) / 4, 256, 0, stream>>>(Qb, Kb, Vb, c_col, bias_c, off_c, el_c, O2, NC);

  // ---- O-projections + residual: x = x_all + concat(O2@o2_w, O1@o1_w)
  // (order: O1-proj first so H's overlay region (Vb/O1) is dead afterwards)
  gemm_kernel<1, bf16, float, bf16><<<g50, 256, 0, stream>>>(
      O1, NT, o1_w, o1_b, x_all + (size_t)NT * HIDDEN, X + (size_t)NT * HIDDEN);
  gemm_kernel<1, bf16, float, bf16><<<g50, 256, 0, stream>>>(O2, NC, o2_w, o2_b, x_all, X);

  // ---- LN2 + FFN + final residual (bf16 X -> fp32 out)
  ln_kernel<bf16><<<(NTOT + 3) / 4, 256, 0, stream>>>(X, ln2_w, ln2_b, Y2, NTOT);
  gemm_kernel<2, bf16, bf16, bf16><<<g100, 256, 0, stream>>>(Y2, NTOT, f1_w, f1_b, nb, H);
  gemm_kernel<1, bf16, bf16, float><<<g100, 256, 0, stream>>>(H, NTOT, f2_w, f2_b, X,
                                                              (float*)d_out);
}